// Round 9
// baseline (1136.849 us; speedup 1.0000x reference)
//
#include <hip/hip_runtime.h>
#include <hip/hip_bf16.h>
#include <stdint.h>

typedef __attribute__((ext_vector_type(8))) short bf16x8;
typedef __attribute__((ext_vector_type(4))) float f32x4;

// ALL-REGISTER design: intermediates never touch LDS. Every second GEMM is
// computed transposed (Y^T = W^T X^T) so each MFMA's D-registers are directly
// the next MFMA's A/B-fragment. Contraction-index mapping (k = 8*fg+j <->
// logical c = 16*(2m+u)+4*fg+(j&3), u=j>>2) is applied consistently to the
// register tiles AND the weight pre-pack, so operands always agree.
//
// x ownership: lane (fr=lane&15, fg=lane>>4) owns row fr, cols 16*nt+4*fg+r
// (nt,r in 0..3). Global I/O: f32x4 per nt -> 64 lanes cover 16 full 64-B
// sectors per instruction (fully coalesced).
//
// LDS map (read-only after preload; NO in-loop hazards, NO barriers/fences):
//   [0, 98304)  96 weight fragments, bf16, frag f at byte f*1024 + lane*16:
//     f 0..23: QKV  (f = sel*8 + hd*2 + m)  A-frags of Wq^T/Wk^T, B-frags of Wv
//     f 24..31: Wp^T (f = 24 + nt*2 + m)
//     f 32..63: W1^T (f = 32 + t*2 + m)
//     f 64..95: W2^T (f = 64 + nt*8 + m)
//   [98304, 100864) params f32: g1@0 be1@64 g2@128 be2@192 bp@256 b2@320 b1@384

static __device__ __forceinline__ unsigned short f2bf(float f) {
    union { __hip_bfloat16 h; unsigned short u; } cv;
    cv.h = __float2bfloat16(f);
    return cv.u;
}
static __device__ __forceinline__ unsigned int f2bf2(float a, float b) {
    return (unsigned int)f2bf(a) | ((unsigned int)f2bf(b) << 16);
}
static __device__ __forceinline__ bf16x8 mk8(uint2 a, uint2 b) {
    union { uint4 u; bf16x8 v; } c;
    c.u = make_uint4(a.x, a.y, b.x, b.y);
    return c.v;
}

__global__ __launch_bounds__(768)
void fused_block(const float* __restrict__ xg,
                 const float* __restrict__ Wq, const float* __restrict__ Wk,
                 const float* __restrict__ Wv, const float* __restrict__ Wp,
                 const float* __restrict__ bp, const float* __restrict__ W1,
                 const float* __restrict__ b1, const float* __restrict__ W2,
                 const float* __restrict__ b2, const float* __restrict__ g1,
                 const float* __restrict__ be1, const float* __restrict__ g2,
                 const float* __restrict__ be2, float* __restrict__ out,
                 int nPairsTotal)
{
    __shared__ __align__(16) unsigned char LDS[100864];

    const int tid  = threadIdx.x;
    const int lane = tid & 63;
    const int wid  = tid >> 6;        // 0..11
    const int fr   = lane & 15;
    const int fg   = lane >> 4;

    // ---------------- weight pre-pack (bf16 fragments, pi-ordered) ----------
    {
        unsigned short* lw = (unsigned short*)LDS;
        #pragma unroll 1
        for (int e = tid; e < 49152; e += 768) {
            int j = e & 7, ln = (e >> 3) & 63, f = e >> 9;
            int fr_ = ln & 15, fg_ = ln >> 4;
            int u = j >> 2, r_ = j & 3;
            float src;
            if (f < 24) {                 // QKV: f = sel*8 + hd*2 + m
                int sel = f >> 3, hd = (f >> 1) & 3, m = f & 1;
                int c = 16*(2*m + u) + 4*fg_ + r_;
                const float* W = (sel == 0) ? Wq : ((sel == 1) ? Wk : Wv);
                src = W[hd*1024 + c*16 + fr_];
            } else if (f < 32) {          // Wp^T: f = 24 + nt*2 + m
                int t = f - 24, nt = t >> 1, m = t & 1;
                int d = 16*(2*m + u) + 4*fg_ + r_;
                src = Wp[d*64 + 16*nt + fr_];
            } else if (f < 64) {          // W1^T: f = 32 + t*2 + m
                int t = f - 32, tt = t >> 1, m = t & 1;
                int c = 16*(2*m + u) + 4*fg_ + r_;
                src = W1[c*256 + 16*tt + fr_];
            } else {                      // W2^T: f = 64 + nt*8 + m
                int t = f - 64, nt = t >> 3, m = t & 7;
                int n1 = 16*(2*m + u) + 4*fg_ + r_;
                src = W2[n1*64 + 16*nt + fr_];
            }
            lw[e] = f2bf(src);
        }
    }
    if (tid < 640) {   // params
        float v;
        if      (tid < 64)  v = g1[tid];
        else if (tid < 128) v = be1[tid - 64];
        else if (tid < 192) v = g2[tid - 128];
        else if (tid < 256) v = be2[tid - 192];
        else if (tid < 320) v = bp[tid - 256];
        else if (tid < 384) v = b2[tid - 320];
        else                v = b1[tid - 384];
        ((float*)(LDS + 98304))[tid] = v;
    }
    __syncthreads();

    const float* PG = (const float*)(LDS + 98304);
    #define WF(F)  (*(const bf16x8*)(LDS + ((F) << 10) + (lane << 4)))
    #define PG4(I) (*(const f32x4*)(PG + (I)))

    const int pipe = blockIdx.x * 12 + wid;   // 256*12 = 3072 pipes
    const f32x4 zf = {0.f, 0.f, 0.f, 0.f};
    const uint2 z2 = make_uint2(0u, 0u);
    const int xoff = fr*64 + 4*fg;            // float offset of (nt=0, r=0)

    // prologue: first tile
    f32x4 xn[4];
    if (pipe < nPairsTotal) {
        const float* xb0 = xg + (size_t)pipe * 1024;
        #pragma unroll
        for (int nt = 0; nt < 4; ++nt)
            xn[nt] = *(const f32x4*)(xb0 + xoff + 16*nt);
    }

    #pragma unroll 1
    for (int gp = pipe; gp < nPairsTotal; gp += 3072) {
        float* ob = out + (size_t)gp * 1024;

        f32x4 xv[4];
        #pragma unroll
        for (int nt = 0; nt < 4; ++nt) xv[nt] = xn[nt];

        {   // next-tile prefetch, in flight across the iteration
            int gpn = gp + 3072;
            if (gpn < nPairsTotal) {
                const float* xbn = xg + (size_t)gpn * 1024;
                #pragma unroll
                for (int nt = 0; nt < 4; ++nt)
                    xn[nt] = *(const f32x4*)(xbn + xoff + 16*nt);
            }
        }

        // ---- LN1 (row = fr; reduce across fg via xor 16,32) -> h frags ----
        bf16x8 hf0, hf1;
        {
            float s = 0.f, ss = 0.f;
            #pragma unroll
            for (int nt = 0; nt < 4; ++nt)
                #pragma unroll
                for (int r = 0; r < 4; ++r) { float v = xv[nt][r]; s += v; ss += v*v; }
            s += __shfl_xor(s, 16, 64); ss += __shfl_xor(ss, 16, 64);
            s += __shfl_xor(s, 32, 64); ss += __shfl_xor(ss, 32, 64);
            float mu  = s * 0.015625f;
            float inv = rsqrtf(ss * 0.015625f - mu*mu + 1e-5f);
            uint2 hw[2];
            #pragma unroll
            for (int m = 0; m < 2; ++m) {
                #pragma unroll
                for (int u = 0; u < 2; ++u) {
                    int nt = 2*m + u;
                    f32x4 gv = PG4(0  + 16*nt + 4*fg);
                    f32x4 bv = PG4(64 + 16*nt + 4*fg);
                    float y0 = (xv[nt][0]-mu)*inv*gv[0] + bv[0];
                    float y1 = (xv[nt][1]-mu)*inv*gv[1] + bv[1];
                    float y2 = (xv[nt][2]-mu)*inv*gv[2] + bv[2];
                    float y3 = (xv[nt][3]-mu)*inv*gv[3] + bv[3];
                    hw[u] = make_uint2(f2bf2(y0,y1), f2bf2(y2,y3));
                }
                if (m == 0) hf0 = mk8(hw[0], hw[1]); else hf1 = mk8(hw[0], hw[1]);
            }
        }

        // ---- QKV (Q^T,K^T transposed; V normal) -> per-lane bf16 tiles ----
        uint2 qb[4], kb[4], vb[4];
        #pragma unroll
        for (int hd = 0; hd < 4; ++hd) {
            f32x4 qa = __builtin_amdgcn_mfma_f32_16x16x32_bf16(WF(hd*2+0),  hf0, zf, 0,0,0);
            qa       = __builtin_amdgcn_mfma_f32_16x16x32_bf16(WF(hd*2+1),  hf1, qa, 0,0,0);
            qb[hd] = make_uint2(f2bf2(qa[0],qa[1]), f2bf2(qa[2],qa[3]));
            f32x4 ka = __builtin_amdgcn_mfma_f32_16x16x32_bf16(WF(8+hd*2+0), hf0, zf, 0,0,0);
            ka       = __builtin_amdgcn_mfma_f32_16x16x32_bf16(WF(8+hd*2+1), hf1, ka, 0,0,0);
            kb[hd] = make_uint2(f2bf2(ka[0],ka[1]), f2bf2(ka[2],ka[3]));
            f32x4 va = __builtin_amdgcn_mfma_f32_16x16x32_bf16(hf0, WF(16+hd*2+0), zf, 0,0,0);
            va       = __builtin_amdgcn_mfma_f32_16x16x32_bf16(hf1, WF(16+hd*2+1), va, 0,0,0);
            vb[hd] = make_uint2(f2bf2(va[0],va[1]), f2bf2(va[2],va[3]));
        }

        // ---- scores S^T = mfma(K,Q); softmax in-reg; O^T = mfma(V,P) ----
        // lane holds S[tq=fr][tk=4fg+r]; rowsum across fg via xor 16,32
        uint2 ob_[4];
        #pragma unroll
        for (int hd = 0; hd < 4; ++hd) {
            f32x4 sa_ = __builtin_amdgcn_mfma_f32_16x16x32_bf16(
                            mk8(kb[hd], z2), mk8(qb[hd], z2), zf, 0,0,0);
            float pw[4], rsum = 0.f;
            #pragma unroll
            for (int r = 0; r < 4; ++r) {
                int tk = 4*fg + r;
                bool valid = (((fr ^ tk) & 8) == 0) && ((tk & 7) <= (fr & 7));
                pw[r] = valid ? __expf(sa_[r] * 0.125f) : 0.f;   // scale = C^-0.5
                rsum += pw[r];
            }
            rsum += __shfl_xor(rsum, 16, 64);
            rsum += __shfl_xor(rsum, 32, 64);
            float pinv = __builtin_amdgcn_rcpf(rsum);
            uint2 pb = make_uint2(f2bf2(pw[0],pw[1]), f2bf2(pw[2],pw[3]));
            f32x4 oa = __builtin_amdgcn_mfma_f32_16x16x32_bf16(
                           mk8(vb[hd], z2), mk8(pb, z2), zf, 0,0,0);
            ob_[hd] = make_uint2(f2bf2(oa[0]*pinv, oa[1]*pinv),
                                 f2bf2(oa[2]*pinv, oa[3]*pinv));
        }

        // ---- proj: sa^T = Wp^T O^T (+bp), residual into xv ----
        #pragma unroll
        for (int nt = 0; nt < 4; ++nt) {
            f32x4 pa = __builtin_amdgcn_mfma_f32_16x16x32_bf16(
                           WF(24 + nt*2 + 0), mk8(ob_[0], ob_[1]), zf, 0,0,0);
            pa       = __builtin_amdgcn_mfma_f32_16x16x32_bf16(
                           WF(24 + nt*2 + 1), mk8(ob_[2], ob_[3]), pa, 0,0,0);
            f32x4 bv = PG4(256 + 16*nt + 4*fg);
            #pragma unroll
            for (int r = 0; r < 4; ++r) xv[nt][r] += pa[r] + bv[r];
        }

        // ---- LN2 -> h2 frags ----
        bf16x8 cf0, cf1;
        {
            float s = 0.f, ss = 0.f;
            #pragma unroll
            for (int nt = 0; nt < 4; ++nt)
                #pragma unroll
                for (int r = 0; r < 4; ++r) { float v = xv[nt][r]; s += v; ss += v*v; }
            s += __shfl_xor(s, 16, 64); ss += __shfl_xor(ss, 16, 64);
            s += __shfl_xor(s, 32, 64); ss += __shfl_xor(ss, 32, 64);
            float mu  = s * 0.015625f;
            float inv = rsqrtf(ss * 0.015625f - mu*mu + 1e-5f);
            uint2 hw[2];
            #pragma unroll
            for (int m = 0; m < 2; ++m) {
                #pragma unroll
                for (int u = 0; u < 2; ++u) {
                    int nt = 2*m + u;
                    f32x4 gv = PG4(128 + 16*nt + 4*fg);
                    f32x4 bv = PG4(192 + 16*nt + 4*fg);
                    float y0 = (xv[nt][0]-mu)*inv*gv[0] + bv[0];
                    float y1 = (xv[nt][1]-mu)*inv*gv[1] + bv[1];
                    float y2 = (xv[nt][2]-mu)*inv*gv[2] + bv[2];
                    float y3 = (xv[nt][3]-mu)*inv*gv[3] + bv[3];
                    hw[u] = make_uint2(f2bf2(y0,y1), f2bf2(y2,y3));
                }
                if (m == 0) cf0 = mk8(hw[0], hw[1]); else cf1 = mk8(hw[0], hw[1]);
            }
        }

        // ---- MLP: ff1^T = W1^T h2^T (relu,+b1) feeds ff2^T = W2^T ff1^T ----
        f32x4 ffa[4];
        #pragma unroll
        for (int nt = 0; nt < 4; ++nt) ffa[nt] = zf;
        #pragma unroll
        for (int m2 = 0; m2 < 8; ++m2) {
            uint2 fb[2];
            #pragma unroll
            for (int u = 0; u < 2; ++u) {
                int t = 2*m2 + u;
                f32x4 fa = __builtin_amdgcn_mfma_f32_16x16x32_bf16(
                               WF(32 + t*2 + 0), cf0, zf, 0,0,0);
                fa       = __builtin_amdgcn_mfma_f32_16x16x32_bf16(
                               WF(32 + t*2 + 1), cf1, fa, 0,0,0);
                f32x4 bv = PG4(384 + 16*t + 4*fg);
                fb[u] = make_uint2(
                    f2bf2(fmaxf(fa[0]+bv[0],0.f), fmaxf(fa[1]+bv[1],0.f)),
                    f2bf2(fmaxf(fa[2]+bv[2],0.f), fmaxf(fa[3]+bv[3],0.f)));
            }
            bf16x8 ffr = mk8(fb[0], fb[1]);
            #pragma unroll
            for (int nt = 0; nt < 4; ++nt)
                ffa[nt] = __builtin_amdgcn_mfma_f32_16x16x32_bf16(
                              WF(64 + nt*8 + m2), ffr, ffa[nt], 0,0,0);
        }

        // ---- +b2, residual 2, store ----
        #pragma unroll
        for (int nt = 0; nt < 4; ++nt) {
            f32x4 bv = PG4(320 + 16*nt + 4*fg);
            f32x4 o;
            #pragma unroll
            for (int r = 0; r < 4; ++r) o[r] = xv[nt][r] + ffa[nt][r] + bv[r];
            *(f32x4*)(ob + xoff + 16*nt) = o;
        }
    }
    #undef WF
    #undef PG4
}

extern "C" void kernel_launch(void* const* d_in, const int* in_sizes, int n_in,
                              void* d_out, int out_size, void* d_ws, size_t ws_size,
                              hipStream_t stream) {
    const float* x   = (const float*)d_in[0];
    const float* Wq  = (const float*)d_in[1];
    const float* Wk  = (const float*)d_in[2];
    const float* Wv  = (const float*)d_in[3];
    const float* Wp  = (const float*)d_in[4];
    const float* bp  = (const float*)d_in[5];
    const float* W1  = (const float*)d_in[6];
    const float* b1  = (const float*)d_in[7];
    const float* W2  = (const float*)d_in[8];
    const float* b2  = (const float*)d_in[9];
    const float* g1  = (const float*)d_in[10];
    const float* be1 = (const float*)d_in[11];
    const float* g2  = (const float*)d_in[12];
    const float* be2 = (const float*)d_in[13];
    int nPairs = in_sizes[0] / 1024;   // (B*T*C) / (2*8*64) = 32768
    fused_block<<<dim3(256), dim3(768), 0, stream>>>(
        x, Wq, Wk, Wv, Wp, bp, W1, b1, W2, b2, g1, be1, g2, be2,
        (float*)d_out, nPairs);
}